// Round 6
// baseline (95.655 us; speedup 1.0000x reference)
//
#include <hip/hip_runtime.h>
#include <hip/hip_bf16.h>

#define S1 2048
#define S2 2048
#define FEAT 768
#define NB 8
#define BM 256
#define BN 256
#define BK 64
#define NKT (FEAT / BK)          // 12 K-tiles
#define ITERS (NKT / 2)          // 6 iterations, 2 K-tiles each
#define HALF_BYTES 16384         // one half-tile: 128 rows x 128 B
#define KT_BYTES   65536         // one K-tile: A0,A1,B0,B1

typedef __attribute__((ext_vector_type(8))) short bf16x8;
typedef __attribute__((ext_vector_type(4))) float f32x4;
typedef __attribute__((ext_vector_type(4))) unsigned short us4;
typedef __attribute__((address_space(1))) const unsigned int gu32;
typedef __attribute__((address_space(3))) unsigned int lu32;

static __device__ __forceinline__ unsigned short f2bf(float x) {
    unsigned u = __builtin_bit_cast(unsigned, x);
    unsigned r = u + 0x7FFFu + ((u >> 16) & 1u);   // RNE
    return (unsigned short)(r >> 16);
}

// ---------------- prepass: A=bf16(m1*wc), B=bf16(m2), Q=m1@wq, D=m2@wd ----------------
__global__ __launch_bounds__(256) void conv_kernel(
    const float* __restrict__ m1, const float* __restrict__ m2,
    const float* __restrict__ wq, const float* __restrict__ wd,
    const float* __restrict__ wc,
    unsigned short* __restrict__ A, unsigned short* __restrict__ Bm,
    float* __restrict__ Q, float* __restrict__ D) {
    int wave = threadIdx.x >> 6;
    int lane = threadIdx.x & 63;
    int g = blockIdx.x * 4 + wave;               // 0 .. 2*NB*S1-1
    bool isA = (g < NB * S1);
    int row = isA ? g : g - NB * S1;
    const float* src = isA ? m1 : m2;
    const float* w   = isA ? wq : wd;
    unsigned short* dst = (isA ? A : Bm) + (size_t)row * FEAT;
    const float4* rp = (const float4*)(src + (size_t)row * FEAT);
    const float4* wp = (const float4*)w;
    const float4* cp = (const float4*)wc;
    float acc = 0.f;
#pragma unroll
    for (int i = 0; i < 3; ++i) {
        int idx = lane + 64 * i;
        float4 a = rp[idx];
        float4 b = wp[idx];
        acc += a.x * b.x + a.y * b.y + a.z * b.z + a.w * b.w;
        float4 c;
        if (isA) c = cp[idx]; else c = float4{1.f, 1.f, 1.f, 1.f};
        us4 v = { f2bf(a.x * c.x), f2bf(a.y * c.y),
                  f2bf(a.z * c.z), f2bf(a.w * c.w) };
        *(us4*)(dst + idx * 4) = v;
    }
#pragma unroll
    for (int s = 32; s; s >>= 1) acc += __shfl_xor(acc, s, 64);
    if (lane == 0) (isA ? Q : D)[row] = acc;
}

// ---------------- 256x256 tile, BK=64, 8-phase pipelined bf16 NT GEMM ----------------
// LDS per K-tile: [A0|A1|B0|B1] halves of 128 rows x 128 B. Slot swizzle
// slot' = slot ^ (row&7) applied on the pre-swizzled global SOURCE col
// (linear LDS dest for global_load_lds, rule #21) and on the ds_read col.
// Wave read: each of 32 banks gets exactly 8 touches -> data-minimum cycles.
// STAGE_H: one half-tile = 2 global_load_lds per thread (8 rows/wave/instr).
#define STAGE_H(_kts, _half) do {                                                 \
    const char* _s = ((_half) < 2 ? Ab : Bb);                                     \
    const int _ro = ((_half) & 1) * 128;                                          \
    char* _d = ldsb + ((_kts) & 1) * KT_BYTES + (_half) * HALF_BYTES;             \
    _Pragma("unroll")                                                             \
    for (int _i = 0; _i < 2; ++_i) {                                              \
        const int _rb = _i * 64 + wave * 8;                                       \
        __builtin_amdgcn_global_load_lds(                                         \
            (gu32*)(_s + (size_t)(_ro + _rb + srow8) * (FEAT * 2)                 \
                       + (_kts) * (BK * 2) + scol8),                              \
            (lu32*)(_d + _rb * 128), 16, 0, 0);                                   \
    }                                                                             \
} while (0)

__global__ __launch_bounds__(512, 1) void gemm8p_kernel(
    const unsigned short* __restrict__ A, const unsigned short* __restrict__ Bm,
    const float* __restrict__ Q, const float* __restrict__ D,
    float* __restrict__ out) {

    extern __shared__ __align__(16) char ldsb[];   // 2 * 64 KB = 128 KB

    const int bid = blockIdx.x;                    // 512 blocks = 8 XCD * 64
    const int swz = (bid & 7) * 64 + (bid >> 3);   // bijective XCD swizzle
    const int b  = swz >> 6;                       // one batch per XCD chunk
    const int t0 = swz & 63;
    const int tm = t0 >> 3, tn = t0 & 7;

    const int tid  = threadIdx.x;
    const int lane = tid & 63;
    const int wave = tid >> 6;
    const int wm = wave >> 2, wn = wave & 3;       // 2x4 waves, 128x64 out each

    const char* Ab = (const char*)(A + ((size_t)b * S1 + (size_t)tm * BM) * FEAT);
    const char* Bb = (const char*)(Bm + ((size_t)b * S2 + (size_t)tn * BN) * FEAT);

    // staging per-lane constants: lane covers (row lane>>3, slot lane&7),
    // source slot pre-swizzled by row&7 (row base multiple of 8 per instr)
    const int srow8 = lane >> 3;
    const int scol8 = ((lane & 7) ^ (srow8 & 7)) * 16;

    // fragment per-lane constants
    const int fr  = lane & 15;                     // fragment row
    const int kg  = lane >> 4;                     // K-group 0..3
    const int frbase = fr * 128 + ((kg ^ (fr & 7)) << 4);  // ks=0 byte; ks=1 = ^64

    f32x4 acc[8][4];
#pragma unroll
    for (int m = 0; m < 8; ++m)
#pragma unroll
        for (int n = 0; n < 4; ++n) acc[m][n] = (f32x4)0.f;

    bf16x8 aR0[4], aR1[4];                         // current mh quadrant, ks=0/1
    bf16x8 bR0[4], bR1[4];                         // all 4 n, ks=0/1

    // ---- prologue: K0 all 4 halves + K1-A0; wait K0 landed (1 half in flight) ----
    STAGE_H(0, 0); STAGE_H(0, 1); STAGE_H(0, 2); STAGE_H(0, 3);
    STAGE_H(1, 0);
    asm volatile("s_waitcnt vmcnt(2)" ::: "memory");
    __builtin_amdgcn_s_barrier();
    asm volatile("" ::: "memory");

    for (int t = 0; t < ITERS; ++t) {
#pragma unroll
        for (int p = 0; p < 8; ++p) {
            const int ktc = 2 * t + (p >> 2);      // K-tile this phase computes
            const char* buf = ldsb + (size_t)(ktc & 1) * KT_BYTES;
            const char* lA = buf + wm * HALF_BYTES;
            const char* lB = buf + 2 * HALF_BYTES + (wn >> 1) * HALF_BYTES
                                 + (wn & 1) * 8192;
            const int q  = p & 3;
            const int mh = q >> 1, nh = q & 1;

            // ---- frag ds_reads for THIS phase's cluster (12/4/8/0 pattern) ----
            if (q == 0) {
#pragma unroll
                for (int mm = 0; mm < 4; ++mm) {
                    aR0[mm] = *(const bf16x8*)(lA + mm * 2048 + frbase);
                    aR1[mm] = *(const bf16x8*)(lA + mm * 2048 + (frbase ^ 64));
                }
#pragma unroll
                for (int nn = 0; nn < 2; ++nn) {
                    bR0[nn] = *(const bf16x8*)(lB + nn * 2048 + frbase);
                    bR1[nn] = *(const bf16x8*)(lB + nn * 2048 + (frbase ^ 64));
                }
            } else if (q == 1) {
#pragma unroll
                for (int nn = 2; nn < 4; ++nn) {
                    bR0[nn] = *(const bf16x8*)(lB + nn * 2048 + frbase);
                    bR1[nn] = *(const bf16x8*)(lB + nn * 2048 + (frbase ^ 64));
                }
            } else if (q == 2) {
#pragma unroll
                for (int mm = 0; mm < 4; ++mm) {
                    aR0[mm] = *(const bf16x8*)(lA + 8192 + mm * 2048 + frbase);
                    aR1[mm] = *(const bf16x8*)(lA + 8192 + mm * 2048 + (frbase ^ 64));
                }
            }

            // ---- stage exactly one half-tile (stream shifted +5 slots) ----
            {
                const int kts  = 2 * t + ((p + 5) >> 2);
                const int half = (p + 5) & 3;
                if (kts < NKT) STAGE_H(kts, half);
            }

            asm volatile("" ::: "memory");
            __builtin_amdgcn_s_barrier();
            asm volatile("" ::: "memory");

            // ---- 16 MFMA: quadrant (mh, nh) x K=64 ----
            __builtin_amdgcn_s_setprio(1);
#pragma unroll
            for (int mm = 0; mm < 4; ++mm)
#pragma unroll
                for (int nn = 0; nn < 2; ++nn) {
                    const int mg = mh * 4 + mm, ng = nh * 2 + nn;
                    acc[mg][ng] = __builtin_amdgcn_mfma_f32_16x16x32_bf16(
                        aR0[mm], bR0[ng], acc[mg][ng], 0, 0, 0);
                    acc[mg][ng] = __builtin_amdgcn_mfma_f32_16x16x32_bf16(
                        aR1[mm], bR1[ng], acc[mg][ng], 0, 0, 0);
                }
            __builtin_amdgcn_s_setprio(0);

            // ---- counted vmcnt, only at phase 3 / phase 7 ends ----
            if (p == 3) {
                if (t == ITERS - 1) asm volatile("s_waitcnt vmcnt(0)" ::: "memory");
                else                asm volatile("s_waitcnt vmcnt(2)" ::: "memory");
            }
            if (p == 7 && t < ITERS - 1)
                asm volatile("s_waitcnt vmcnt(2)" ::: "memory");

            asm volatile("" ::: "memory");
            __builtin_amdgcn_s_barrier();
            asm volatile("" ::: "memory");
        }
    }

    // ---------------- epilogue: + Q[j] + D[k], store fp32 ----------------
    const float* Qb = Q + b * S1 + tm * BM;
    const float* Db = D + b * S2 + tn * BN;
    float dv[4];
#pragma unroll
    for (int n = 0; n < 4; ++n) dv[n] = Db[wn * 64 + n * 16 + fr];

    const size_t outbase = ((size_t)b * S1 + (size_t)tm * BM) * S2 + (size_t)tn * BN;
#pragma unroll
    for (int m = 0; m < 8; ++m) {
#pragma unroll
        for (int i = 0; i < 4; ++i) {
            int rl = wm * 128 + m * 16 + kg * 4 + i;
            float qv = Qb[rl];
            float* orow = out + outbase + (size_t)rl * S2 + wn * 64;
#pragma unroll
            for (int n = 0; n < 4; ++n)
                orow[n * 16 + fr] = acc[m][n][i] + qv + dv[n];
        }
    }
}

// ================= fallback path (round-1, fp32 inputs) =================
__global__ __launch_bounds__(256) void qd_kernel(
    const float* __restrict__ m1, const float* __restrict__ m2,
    const float* __restrict__ wq, const float* __restrict__ wd,
    float* __restrict__ Q, float* __restrict__ D) {
    int wave = threadIdx.x >> 6;
    int lane = threadIdx.x & 63;
    int g = blockIdx.x * 4 + wave;
    const float* src; const float* w; float* dst; int row;
    if (g < NB * S1) { src = m1; w = wq; dst = Q; row = g; }
    else             { src = m2; w = wd; dst = D; row = g - NB * S1; }
    const float4* rp = (const float4*)(src + (size_t)row * FEAT);
    const float4* wp = (const float4*)w;
    float acc = 0.f;
#pragma unroll
    for (int i = 0; i < 3; ++i) {
        float4 a = rp[lane + 64 * i];
        float4 b = wp[lane + 64 * i];
        acc += a.x * b.x + a.y * b.y + a.z * b.z + a.w * b.w;
    }
#pragma unroll
    for (int s = 32; s; s >>= 1) acc += __shfl_xor(acc, s, 64);
    if (lane == 0) dst[row] = acc;
}

__global__ __launch_bounds__(256) void gemm_kernel(
    const float* __restrict__ m1, const float* __restrict__ m2,
    const float* __restrict__ wc,
    const float* __restrict__ Q, const float* __restrict__ D,
    float* __restrict__ out) {

    __shared__ __align__(16) char sA[128 * 64 * 2];
    __shared__ __align__(16) char sB[128 * 64 * 2];
    __shared__ float wcs[FEAT];

    const int tid = threadIdx.x;
    const int blk = blockIdx.x;
    const int b  = blk >> 8;
    const int t  = blk & 255;
    const int tm = t >> 4, tn = t & 15;

    for (int i = tid; i < FEAT; i += 256) wcs[i] = wc[i];

    const float* Abase = m1 + ((size_t)b * S1 + (size_t)tm * 128) * FEAT;
    const float* Bbase = m2 + ((size_t)b * S2 + (size_t)tn * 128) * FEAT;

    const int lane = tid & 63;
    const int wave = tid >> 6;
    const int wm = wave >> 1, wn = wave & 1;

    f32x4 acc[4][4];
#pragma unroll
    for (int m = 0; m < 4; ++m)
#pragma unroll
        for (int n = 0; n < 4; ++n) acc[m][n] = (f32x4)0.f;

    const int col4 = tid & 15;
    const int row0 = tid >> 4;

    __syncthreads();

    for (int ks = 0; ks < FEAT / 64; ++ks) {
        float4 wc4 = *(const float4*)&wcs[ks * 64 + col4 * 4];
        const float4* Ak = (const float4*)(Abase + ks * 64);
        const float4* Bk = (const float4*)(Bbase + ks * 64);

        __syncthreads();
#pragma unroll
        for (int i = 0; i < 8; ++i) {
            int r = row0 + 16 * i;
            float4 a = Ak[(size_t)r * (FEAT / 4) + col4];
            us4 av = { f2bf(a.x * wc4.x), f2bf(a.y * wc4.y),
                       f2bf(a.z * wc4.z), f2bf(a.w * wc4.w) };
            int off = r * 128 + ((col4 * 8) ^ ((r & 7) << 4));
            *(us4*)(sA + off) = av;
        }
#pragma unroll
        for (int i = 0; i < 8; ++i) {
            int r = row0 + 16 * i;
            float4 v = Bk[(size_t)r * (FEAT / 4) + col4];
            us4 bv = { f2bf(v.x), f2bf(v.y), f2bf(v.z), f2bf(v.w) };
            int off = r * 128 + ((col4 * 8) ^ ((r & 7) << 4));
            *(us4*)(sB + off) = bv;
        }
        __syncthreads();

#pragma unroll
        for (int s = 0; s < 2; ++s) {
            bf16x8 af[4], bfr[4];
#pragma unroll
            for (int m = 0; m < 4; ++m) {
                int r = wm * 64 + m * 16 + (lane & 15);
                int coff = (s * 64 + (lane >> 4) * 16) ^ ((r & 7) << 4);
                af[m] = *(const bf16x8*)(sA + r * 128 + coff);
            }
#pragma unroll
            for (int n = 0; n < 4; ++n) {
                int r = wn * 64 + n * 16 + (lane & 15);
                int coff = (s * 64 + (lane >> 4) * 16) ^ ((r & 7) << 4);
                bfr[n] = *(const bf16x8*)(sB + r * 128 + coff);
            }
#pragma unroll
            for (int m = 0; m < 4; ++m)
#pragma unroll
                for (int n = 0; n < 4; ++n)
                    acc[m][n] = __builtin_amdgcn_mfma_f32_16x16x32_bf16(
                        af[m], bfr[n], acc[m][n], 0, 0, 0);
        }
    }

    const float* Qb = Q + b * S1 + tm * 128;
    const float* Db = D + b * S2 + tn * 128;
    float dv[4];
#pragma unroll
    for (int n = 0; n < 4; ++n) dv[n] = Db[wn * 64 + n * 16 + (lane & 15)];

    const size_t outbase = ((size_t)b * S1 + (size_t)tm * 128) * S2 + (size_t)tn * 128;
#pragma unroll
    for (int m = 0; m < 4; ++m) {
#pragma unroll
        for (int i = 0; i < 4; ++i) {
            int rl = wm * 64 + m * 16 + (lane >> 4) * 4 + i;
            float qv = Qb[rl];
            float* orow = out + outbase + (size_t)rl * S2 + wn * 64;
#pragma unroll
            for (int n = 0; n < 4; ++n) {
                int cl = n * 16 + (lane & 15);
                orow[cl] = acc[m][n][i] + qv + dv[n];
            }
        }
    }
}

extern "C" void kernel_launch(void* const* d_in, const int* in_sizes, int n_in,
                              void* d_out, int out_size, void* d_ws, size_t ws_size,
                              hipStream_t stream) {
    const float* m1 = (const float*)d_in[0];
    const float* m2 = (const float*)d_in[1];
    const float* wq = (const float*)d_in[2];
    const float* wd = (const float*)d_in[3];
    const float* wc = (const float*)d_in[4];
    float* out = (float*)d_out;

    const size_t elems = (size_t)NB * S1 * FEAT;
    const size_t need = 2 * elems * sizeof(unsigned short)
                      + (size_t)(NB * S1 + NB * S2) * sizeof(float);

    if (ws_size >= need) {
        unsigned short* Abuf = (unsigned short*)d_ws;
        unsigned short* Bbuf = Abuf + elems;
        float* Q  = (float*)(Bbuf + elems);
        float* Dv = Q + NB * S1;
        conv_kernel<<<(NB * S1 + NB * S2) / 4, 256, 0, stream>>>(
            m1, m2, wq, wd, wc, Abuf, Bbuf, Q, Dv);
        gemm8p_kernel<<<NB * (S1 / BM) * (S2 / BN), 512, 2 * KT_BYTES, stream>>>(
            Abuf, Bbuf, Q, Dv, out);
    } else {
        float* Q  = (float*)d_ws;
        float* Dv = Q + NB * S1;
        qd_kernel<<<(2 * NB * S1) / 4, 256, 0, stream>>>(m1, m2, wq, wd, Q, Dv);
        gemm_kernel<<<NB * 256, 256, 0, stream>>>(m1, m2, wc, Q, Dv, out);
    }
}

// Round 7
// 88.305 us; speedup vs baseline: 1.0832x; 1.0832x over previous
//
#include <hip/hip_runtime.h>
#include <hip/hip_bf16.h>

#define S1 2048
#define S2 2048
#define FEAT 768
#define NB 8
#define BK 64
#define NKT (FEAT / BK)          // 12 K-steps

typedef __attribute__((ext_vector_type(8))) short bf16x8;
typedef __attribute__((ext_vector_type(4))) float f32x4;
typedef __attribute__((ext_vector_type(4))) unsigned short us4;
typedef __attribute__((address_space(1))) const unsigned int gu32;
typedef __attribute__((address_space(3))) unsigned int lu32;

static __device__ __forceinline__ unsigned short f2bf(float x) {
    unsigned u = __builtin_bit_cast(unsigned, x);
    unsigned r = u + 0x7FFFu + ((u >> 16) & 1u);   // RNE
    return (unsigned short)(r >> 16);
}

// ---------------- prepass: A=bf16(m1*wc), B=bf16(m2), Q=m1@wq, D=m2@wd ----------------
__global__ __launch_bounds__(256) void conv_kernel(
    const float* __restrict__ m1, const float* __restrict__ m2,
    const float* __restrict__ wq, const float* __restrict__ wd,
    const float* __restrict__ wc,
    unsigned short* __restrict__ A, unsigned short* __restrict__ Bm,
    float* __restrict__ Q, float* __restrict__ D) {
    int wave = threadIdx.x >> 6;
    int lane = threadIdx.x & 63;
    int g = blockIdx.x * 4 + wave;               // 0 .. 2*NB*S1-1
    bool isA = (g < NB * S1);
    int row = isA ? g : g - NB * S1;
    const float* src = isA ? m1 : m2;
    const float* w   = isA ? wq : wd;
    unsigned short* dst = (isA ? A : Bm) + (size_t)row * FEAT;
    const float4* rp = (const float4*)(src + (size_t)row * FEAT);
    const float4* wp = (const float4*)w;
    const float4* cp = (const float4*)wc;
    float acc = 0.f;
#pragma unroll
    for (int i = 0; i < 3; ++i) {
        int idx = lane + 64 * i;
        float4 a = rp[idx];
        float4 b = wp[idx];
        acc += a.x * b.x + a.y * b.y + a.z * b.z + a.w * b.w;
        float4 c;
        if (isA) c = cp[idx]; else c = float4{1.f, 1.f, 1.f, 1.f};
        us4 v = { f2bf(a.x * c.x), f2bf(a.y * c.y),
                  f2bf(a.z * c.z), f2bf(a.w * c.w) };
        *(us4*)(dst + idx * 4) = v;
    }
#pragma unroll
    for (int s = 32; s; s >>= 1) acc += __shfl_xor(acc, s, 64);
    if (lane == 0) (isA ? Q : D)[row] = acc;
}

// ---------------- 128x128 tile, BK=64, single-buffer m97-structure GEMM ----------------
// 256 thr / 4 waves (2x2 of 64x64 out), 32 KB LDS, 3 blocks/CU.
// LDS rows 128 B; slot swizzle slot' = slot ^ (row&7): pre-swizzled global
// source col for global_load_lds (linear LDS dest, rule #21), XOR'd ds_read
// col. Proven conflict-free + correct in R2/R4/R6.
__global__ __launch_bounds__(256, 3) void gemm128_kernel(
    const unsigned short* __restrict__ A, const unsigned short* __restrict__ Bm,
    const float* __restrict__ Q, const float* __restrict__ D,
    float* __restrict__ out) {

    __shared__ __align__(16) char sA[128 * 128];   // 16 KB
    __shared__ __align__(16) char sB[128 * 128];   // 16 KB

    // two-level swizzle: XCD owns batch (bid&7); within XCD walk 8x8 quadrants
    // so the resident tile window's A+B panels (3.1 MB) fit the 4 MB L2.
    const int bid = blockIdx.x;                    // 0..2047
    const int b   = bid & 7;                       // batch == XCD
    const int idx = bid >> 3;                      // 0..255 within batch
    const int qd  = idx >> 6;                      // quadrant 0..3
    const int w64 = idx & 63;
    const int tm  = ((qd >> 1) << 3) | (w64 >> 3);
    const int tn  = ((qd & 1) << 3) | (w64 & 7);

    const int tid  = threadIdx.x;
    const int lane = tid & 63;
    const int wave = tid >> 6;
    const int wm = wave >> 1, wn = wave & 1;       // 2x2 waves, 64x64 out each

    const char* Ab = (const char*)(A + ((size_t)b * S1 + (size_t)tm * 128) * FEAT);
    const char* Bb = (const char*)(Bm + ((size_t)b * S2 + (size_t)tn * 128) * FEAT);

    const int srow = lane >> 3;                            // 0..7
    const int scol = ((lane & 7) ^ (srow & 7)) * 16;       // pre-swizzled source col

    const int fr = lane & 15;                              // fragment row
    const int kg = lane >> 4;                              // K-group 0..3

    f32x4 acc[4][4];
#pragma unroll
    for (int m = 0; m < 4; ++m)
#pragma unroll
        for (int n = 0; n < 4; ++n) acc[m][n] = (f32x4)0.f;

    for (int kt = 0; kt < NKT; ++kt) {
        __syncthreads();                                   // prev frag reads done
#pragma unroll
        for (int i = 0; i < 4; ++i) {                      // stage A,B: 4 rows-of-8 each
            const int rb = wave * 32 + i * 8;
            __builtin_amdgcn_global_load_lds(
                (gu32*)(Ab + (size_t)(rb + srow) * (FEAT * 2) + kt * (BK * 2) + scol),
                (lu32*)(sA + rb * 128), 16, 0, 0);
            __builtin_amdgcn_global_load_lds(
                (gu32*)(Bb + (size_t)(rb + srow) * (FEAT * 2) + kt * (BK * 2) + scol),
                (lu32*)(sB + rb * 128), 16, 0, 0);
        }
        __syncthreads();                                   // drains vmcnt, tile ready

#pragma unroll
        for (int s = 0; s < 2; ++s) {                      // two K=32 sub-steps
            bf16x8 af[4], bfr[4];
#pragma unroll
            for (int m = 0; m < 4; ++m) {
                int r = wm * 64 + m * 16 + fr;
                int coff = (s * 64 + kg * 16) ^ ((r & 7) << 4);
                af[m] = *(const bf16x8*)(sA + r * 128 + coff);
            }
#pragma unroll
            for (int n = 0; n < 4; ++n) {
                int r = wn * 64 + n * 16 + fr;
                int coff = (s * 64 + kg * 16) ^ ((r & 7) << 4);
                bfr[n] = *(const bf16x8*)(sB + r * 128 + coff);
            }
#pragma unroll
            for (int m = 0; m < 4; ++m)
#pragma unroll
                for (int n = 0; n < 4; ++n)
                    acc[m][n] = __builtin_amdgcn_mfma_f32_16x16x32_bf16(
                        af[m], bfr[n], acc[m][n], 0, 0, 0);
        }
    }

    // ---------------- epilogue: + Q[j] + D[k], store fp32 ----------------
    const float* Qb = Q + b * S1 + tm * 128;
    const float* Db = D + b * S2 + tn * 128;
    float dv[4];
#pragma unroll
    for (int n = 0; n < 4; ++n) dv[n] = Db[wn * 64 + n * 16 + fr];

    const size_t outbase = ((size_t)b * S1 + (size_t)tm * 128) * S2 + (size_t)tn * 128;
#pragma unroll
    for (int m = 0; m < 4; ++m) {
#pragma unroll
        for (int i = 0; i < 4; ++i) {
            int rl = wm * 64 + m * 16 + kg * 4 + i;
            float qv = Qb[rl];
            float* orow = out + outbase + (size_t)rl * S2 + wn * 64;
#pragma unroll
            for (int n = 0; n < 4; ++n)
                orow[n * 16 + fr] = acc[m][n][i] + qv + dv[n];
        }
    }
}

// ================= fallback path (round-1, fp32 inputs) =================
__global__ __launch_bounds__(256) void qd_kernel(
    const float* __restrict__ m1, const float* __restrict__ m2,
    const float* __restrict__ wq, const float* __restrict__ wd,
    float* __restrict__ Q, float* __restrict__ D) {
    int wave = threadIdx.x >> 6;
    int lane = threadIdx.x & 63;
    int g = blockIdx.x * 4 + wave;
    const float* src; const float* w; float* dst; int row;
    if (g < NB * S1) { src = m1; w = wq; dst = Q; row = g; }
    else             { src = m2; w = wd; dst = D; row = g - NB * S1; }
    const float4* rp = (const float4*)(src + (size_t)row * FEAT);
    const float4* wp = (const float4*)w;
    float acc = 0.f;
#pragma unroll
    for (int i = 0; i < 3; ++i) {
        float4 a = rp[lane + 64 * i];
        float4 b = wp[lane + 64 * i];
        acc += a.x * b.x + a.y * b.y + a.z * b.z + a.w * b.w;
    }
#pragma unroll
    for (int s = 32; s; s >>= 1) acc += __shfl_xor(acc, s, 64);
    if (lane == 0) dst[row] = acc;
}

__global__ __launch_bounds__(256) void gemm_kernel(
    const float* __restrict__ m1, const float* __restrict__ m2,
    const float* __restrict__ wc,
    const float* __restrict__ Q, const float* __restrict__ D,
    float* __restrict__ out) {

    __shared__ __align__(16) char sA[128 * 64 * 2];
    __shared__ __align__(16) char sB[128 * 64 * 2];
    __shared__ float wcs[FEAT];

    const int tid = threadIdx.x;
    const int blk = blockIdx.x;
    const int b  = blk >> 8;
    const int t  = blk & 255;
    const int tm = t >> 4, tn = t & 15;

    for (int i = tid; i < FEAT; i += 256) wcs[i] = wc[i];

    const float* Abase = m1 + ((size_t)b * S1 + (size_t)tm * 128) * FEAT;
    const float* Bbase = m2 + ((size_t)b * S2 + (size_t)tn * 128) * FEAT;

    const int lane = tid & 63;
    const int wave = tid >> 6;
    const int wm = wave >> 1, wn = wave & 1;

    f32x4 acc[4][4];
#pragma unroll
    for (int m = 0; m < 4; ++m)
#pragma unroll
        for (int n = 0; n < 4; ++n) acc[m][n] = (f32x4)0.f;

    const int col4 = tid & 15;
    const int row0 = tid >> 4;

    __syncthreads();

    for (int ks = 0; ks < FEAT / 64; ++ks) {
        float4 wc4 = *(const float4*)&wcs[ks * 64 + col4 * 4];
        const float4* Ak = (const float4*)(Abase + ks * 64);
        const float4* Bk = (const float4*)(Bbase + ks * 64);

        __syncthreads();
#pragma unroll
        for (int i = 0; i < 8; ++i) {
            int r = row0 + 16 * i;
            float4 a = Ak[(size_t)r * (FEAT / 4) + col4];
            us4 av = { f2bf(a.x * wc4.x), f2bf(a.y * wc4.y),
                       f2bf(a.z * wc4.z), f2bf(a.w * wc4.w) };
            int off = r * 128 + ((col4 * 8) ^ ((r & 7) << 4));
            *(us4*)(sA + off) = av;
        }
#pragma unroll
        for (int i = 0; i < 8; ++i) {
            int r = row0 + 16 * i;
            float4 v = Bk[(size_t)r * (FEAT / 4) + col4];
            us4 bv = { f2bf(v.x), f2bf(v.y), f2bf(v.z), f2bf(v.w) };
            int off = r * 128 + ((col4 * 8) ^ ((r & 7) << 4));
            *(us4*)(sB + off) = bv;
        }
        __syncthreads();

#pragma unroll
        for (int s = 0; s < 2; ++s) {
            bf16x8 af[4], bfr[4];
#pragma unroll
            for (int m = 0; m < 4; ++m) {
                int r = wm * 64 + m * 16 + (lane & 15);
                int coff = (s * 64 + (lane >> 4) * 16) ^ ((r & 7) << 4);
                af[m] = *(const bf16x8*)(sA + r * 128 + coff);
            }
#pragma unroll
            for (int n = 0; n < 4; ++n) {
                int r = wn * 64 + n * 16 + (lane & 15);
                int coff = (s * 64 + (lane >> 4) * 16) ^ ((r & 7) << 4);
                bfr[n] = *(const bf16x8*)(sB + r * 128 + coff);
            }
#pragma unroll
            for (int m = 0; m < 4; ++m)
#pragma unroll
                for (int n = 0; n < 4; ++n)
                    acc[m][n] = __builtin_amdgcn_mfma_f32_16x16x32_bf16(
                        af[m], bfr[n], acc[m][n], 0, 0, 0);
        }
    }

    const float* Qb = Q + b * S1 + tm * 128;
    const float* Db = D + b * S2 + tn * 128;
    float dv[4];
#pragma unroll
    for (int n = 0; n < 4; ++n) dv[n] = Db[wn * 64 + n * 16 + (lane & 15)];

    const size_t outbase = ((size_t)b * S1 + (size_t)tm * 128) * S2 + (size_t)tn * 128;
#pragma unroll
    for (int m = 0; m < 4; ++m) {
#pragma unroll
        for (int i = 0; i < 4; ++i) {
            int rl = wm * 64 + m * 16 + (lane >> 4) * 4 + i;
            float qv = Qb[rl];
            float* orow = out + outbase + (size_t)rl * S2 + wn * 64;
#pragma unroll
            for (int n = 0; n < 4; ++n) {
                int cl = n * 16 + (lane & 15);
                orow[cl] = acc[m][n][i] + qv + dv[n];
            }
        }
    }
}

extern "C" void kernel_launch(void* const* d_in, const int* in_sizes, int n_in,
                              void* d_out, int out_size, void* d_ws, size_t ws_size,
                              hipStream_t stream) {
    const float* m1 = (const float*)d_in[0];
    const float* m2 = (const float*)d_in[1];
    const float* wq = (const float*)d_in[2];
    const float* wd = (const float*)d_in[3];
    const float* wc = (const float*)d_in[4];
    float* out = (float*)d_out;

    const size_t elems = (size_t)NB * S1 * FEAT;
    const size_t need = 2 * elems * sizeof(unsigned short)
                      + (size_t)(NB * S1 + NB * S2) * sizeof(float);

    if (ws_size >= need) {
        unsigned short* Abuf = (unsigned short*)d_ws;
        unsigned short* Bbuf = Abuf + elems;
        float* Q  = (float*)(Bbuf + elems);
        float* Dv = Q + NB * S1;
        conv_kernel<<<(NB * S1 + NB * S2) / 4, 256, 0, stream>>>(
            m1, m2, wq, wd, wc, Abuf, Bbuf, Q, Dv);
        gemm128_kernel<<<NB * 16 * 16, 256, 0, stream>>>(Abuf, Bbuf, Q, Dv, out);
    } else {
        float* Q  = (float*)d_ws;
        float* Dv = Q + NB * S1;
        qd_kernel<<<(2 * NB * S1) / 4, 256, 0, stream>>>(m1, m2, wq, wd, Q, Dv);
        gemm_kernel<<<NB * 256, 256, 0, stream>>>(m1, m2, wc, Q, Dv, out);
    }
}